// Round 1
// baseline (317.184 us; speedup 1.0000x reference)
//
#include <hip/hip_runtime.h>

typedef __bf16 bf16x8 __attribute__((ext_vector_type(8)));
typedef float floatx4 __attribute__((ext_vector_type(4)));

#define NCH 64   // number of time chunks
#define CLEN 32  // chunk length (NCH*CLEN = 2048)

__device__ __forceinline__ unsigned short f2bf(float f) {
  unsigned int u = __builtin_bit_cast(unsigned int, f);
  u += 0x7fff + ((u >> 16) & 1);
  return (unsigned short)(u >> 16);
}

// ---------------- casts ----------------
__global__ void cast_x_kernel(const float* __restrict__ in, unsigned short* __restrict__ out) {
  int i = blockIdx.x * blockDim.x + threadIdx.x;  // exact: 8192 blk * 256 thr * 4 elems
  float4 v = ((const float4*)in)[i];
  ushort4 o;
  o.x = f2bf(v.x); o.y = f2bf(v.y); o.z = f2bf(v.z); o.w = f2bf(v.w);
  ((ushort4*)out)[i] = o;
}

// W (1024 x ncols) fp32 -> WT (ncols x 1024) bf16
__global__ void tcast_kernel(const float* __restrict__ W, unsigned short* __restrict__ WT, int ncols) {
  __shared__ float tile[32][33];
  int n0 = blockIdx.x * 32, k0 = blockIdx.y * 32;
  int tx = threadIdx.x, ty = threadIdx.y;
  tile[ty][tx] = W[(size_t)(k0 + ty) * ncols + n0 + tx];
  __syncthreads();
  WT[(size_t)(n0 + ty) * 1024 + k0 + tx] = f2bf(tile[tx][ty]);
}

// ---------------- GEMM (bf16 MFMA, K=1024 fixed) ----------------
// EPI==1: gemm1 epilogue -> silu/sigmoid/lam.  EPI==0: gemm2 -> out + bias.
template <int EPI>
__global__ __launch_bounds__(256) void gemm_kernel(
    const unsigned short* __restrict__ A, const unsigned short* __restrict__ BT,
    const float* __restrict__ bias, const float* __restrict__ lb,
    float* __restrict__ out0, float* __restrict__ out1, float* __restrict__ out2) {
  __shared__ alignas(16) unsigned short As[128 * 40];
  __shared__ alignas(16) unsigned short Bs[128 * 40];
  const int m0 = blockIdx.x * 128, n0 = blockIdx.y * 128;
  const int tid = threadIdx.x;
  const int lane = tid & 63, wave = tid >> 6;
  const int wm = (wave >> 1) * 64, wn = (wave & 1) * 64;
  const int mrow = lane & 15, q = lane >> 4;
  floatx4 acc[4][4] = {};
  const int r = tid >> 1, sg = tid & 1;
  const uint4* ag = (const uint4*)(A + (size_t)(m0 + r) * 1024 + sg * 16);
  const uint4* bg = (const uint4*)(BT + (size_t)(n0 + r) * 1024 + sg * 16);
  uint4* al = (uint4*)&As[r * 40 + sg * 16];
  uint4* bl = (uint4*)&Bs[r * 40 + sg * 16];
  for (int kt = 0; kt < 1024; kt += 32) {
    uint4 a0 = ag[0], a1 = ag[1], b0 = bg[0], b1 = bg[1];
    ag += 4; bg += 4;
    __syncthreads();
    al[0] = a0; al[1] = a1; bl[0] = b0; bl[1] = b1;
    __syncthreads();
    bf16x8 af[4], bf[4];
#pragma unroll
    for (int i = 0; i < 4; i++) af[i] = *(const bf16x8*)&As[(wm + i * 16 + mrow) * 40 + q * 8];
#pragma unroll
    for (int j = 0; j < 4; j++) bf[j] = *(const bf16x8*)&Bs[(wn + j * 16 + mrow) * 40 + q * 8];
#pragma unroll
    for (int i = 0; i < 4; i++)
#pragma unroll
      for (int j = 0; j < 4; j++)
        acc[i][j] = __builtin_amdgcn_mfma_f32_16x16x32_bf16(af[i], bf[j], acc[i][j], 0, 0, 0);
  }
#pragma unroll
  for (int i = 0; i < 4; i++) {
    const int rbase = m0 + wm + i * 16 + q * 4;
#pragma unroll
    for (int j = 0; j < 4; j++) {
      const int c = n0 + wn + j * 16 + mrow;
      const float bi = bias[c];
#pragma unroll
      for (int g = 0; g < 4; g++) {
        float v = acc[i][j][g] + bi;
        size_t ro = (size_t)(rbase + g) * 1024;
        if (EPI == 0) {
          out0[ro + c] = v;
        } else {
          int segc = c >> 10, cl = c & 1023;
          float s = 1.f / (1.f + __expf(-v));
          if (segc == 0) out0[ro + cl] = v * s;                       // silu(inp)
          else if (segc == 1) out1[ro + cl] = s;                     // sigmoid(og)
          else { float L = lb[cl]; out2[ro + cl] = L + (1.f - L) * s; } // lam
        }
      }
    }
  }
}

// ---------------- chunked bidirectional scan ----------------
// channel layout per (b,h): ch = dd*2+e;  a=lam[dd], u=(1-lam[dd])*inp[e]
// idx = (c*4 + b)*512 + h
__global__ void scan_passA(const float* __restrict__ lam, const float* __restrict__ inp,
                           float* __restrict__ sumA, float* __restrict__ sumBf,
                           float* __restrict__ sumBr) {
  int idx = blockIdx.x * 256 + threadIdx.x;
  int h = idx & 511, cb = idx >> 9, b = cb & 3, c = cb >> 2;
  long base = ((long)c * CLEN * 4 + b) * 1024 + 2 * h;
  float p0 = 1.f, p1 = 1.f;
  float s00 = 0.f, s01 = 0.f, s10 = 0.f, s11 = 0.f;
  float r00 = 0.f, r01 = 0.f, r10 = 0.f, r11 = 0.f;
  for (int t = 0; t < CLEN; t++) {
    float2 l = *(const float2*)(lam + base);
    float2 ip = *(const float2*)(inp + base);
    base += 4096;
    float omx = 1.f - l.x, omy = 1.f - l.y;
    float u00 = omx * ip.x, u01 = omx * ip.y, u10 = omy * ip.x, u11 = omy * ip.y;
    r00 += p0 * u00; r01 += p0 * u01; r10 += p1 * u10; r11 += p1 * u11;
    s00 = l.x * s00 + u00; s01 = l.x * s01 + u01;
    s10 = l.y * s10 + u10; s11 = l.y * s11 + u11;
    p0 *= l.x; p1 *= l.y;
  }
  ((float2*)sumA)[idx] = make_float2(p0, p1);
  ((float4*)sumBf)[idx] = make_float4(s00, s01, s10, s11);
  ((float4*)sumBr)[idx] = make_float4(r00, r01, r10, r11);
}

__global__ void scan_passB(const float* __restrict__ sumA, const float* __restrict__ sumBf,
                           const float* __restrict__ sumBr, float* __restrict__ initF,
                           float* __restrict__ initR) {
  int tid = blockIdx.x * 256 + threadIdx.x;  // 16384
  int dir = tid >> 13;
  int rem = tid & 8191;   // (b*512+h)*4 + ch
  int ch = rem & 3;
  int bh = rem >> 2;
  int dd = ch >> 1;
  if (dir == 0) {
    float H = 0.f;
    for (int c = 0; c < NCH; c++) {
      int si = c * 2048 + bh;
      initF[(size_t)si * 4 + ch] = H;
      H = sumA[(size_t)si * 2 + dd] * H + sumBf[(size_t)si * 4 + ch];
    }
  } else {
    float G = 0.f;
    for (int c = NCH - 1; c >= 0; c--) {
      int si = c * 2048 + bh;
      initR[(size_t)si * 4 + ch] = G;
      G = sumA[(size_t)si * 2 + dd] * G + sumBr[(size_t)si * 4 + ch];
    }
  }
}

__global__ void scan_passC1(const float* __restrict__ lam, const float* __restrict__ inp,
                            const float* __restrict__ og, const float* __restrict__ initF,
                            float* __restrict__ outp) {
  int idx = blockIdx.x * 256 + threadIdx.x;
  int h = idx & 511, cb = idx >> 9, b = cb & 3, c = cb >> 2;
  float4 H = ((const float4*)initF)[idx];
  float h00 = H.x, h01 = H.y, h10 = H.z, h11 = H.w;
  long base = ((long)c * CLEN * 4 + b) * 1024 + 2 * h;
  for (int t = 0; t < CLEN; t++) {
    float2 l = *(const float2*)(lam + base);
    float2 ip = *(const float2*)(inp + base);
    float2 o = *(const float2*)(og + base);
    float omx = 1.f - l.x, omy = 1.f - l.y;
    h00 = l.x * h00 + omx * ip.x; h01 = l.x * h01 + omx * ip.y;
    h10 = l.y * h10 + omy * ip.x; h11 = l.y * h11 + omy * ip.y;
    float2 rr;
    rr.x = h00 * o.x + h10 * o.y;
    rr.y = h01 * o.x + h11 * o.y;
    *(float2*)(outp + base) = rr;
    base += 4096;
  }
}

__global__ void scan_passC2(const float* __restrict__ lam, const float* __restrict__ inp,
                            const float* __restrict__ og, const float* __restrict__ initR,
                            float* __restrict__ outp) {
  int idx = blockIdx.x * 256 + threadIdx.x;
  int h = idx & 511, cb = idx >> 9, b = cb & 3, c = cb >> 2;
  float4 G = ((const float4*)initR)[idx];
  float g00 = G.x, g01 = G.y, g10 = G.z, g11 = G.w;
  long base = ((long)(c * CLEN + CLEN - 1) * 4 + b) * 1024 + 2 * h;
  for (int t = 0; t < CLEN; t++) {
    float2 l = *(const float2*)(lam + base);
    float2 ip = *(const float2*)(inp + base);
    float2 o = *(const float2*)(og + base);
    float2 pv = *(const float2*)(outp + base);
    float omx = 1.f - l.x, omy = 1.f - l.y;
    g00 = omx * ip.x + l.x * g00; g01 = omx * ip.y + l.x * g01;
    g10 = omy * ip.x + l.y * g10; g11 = omy * ip.y + l.y * g11;
    float2 rr;
    rr.x = pv.x + g00 * o.x + g10 * o.y;
    rr.y = pv.y + g01 * o.x + g11 * o.y;
    *(float2*)(outp + base) = rr;
    base -= 4096;
  }
}

// ---------------- layernorm -> bf16 ----------------
__global__ void ln_kernel(const float* __restrict__ xin, const float* __restrict__ gamma,
                          const float* __restrict__ beta, unsigned short* __restrict__ ybf) {
  int row = blockIdx.x;
  int tid = threadIdx.x;
  float4 v = ((const float4*)(xin + (size_t)row * 1024))[tid];
  float s = v.x + v.y + v.z + v.w;
  float s2 = v.x * v.x + v.y * v.y + v.z * v.z + v.w * v.w;
#pragma unroll
  for (int o = 32; o > 0; o >>= 1) { s += __shfl_down(s, o); s2 += __shfl_down(s2, o); }
  __shared__ float red[8];
  int lane = tid & 63, w = tid >> 6;
  if (lane == 0) { red[w] = s; red[w + 4] = s2; }
  __syncthreads();
  if (tid == 0) {
    float a = red[0] + red[1] + red[2] + red[3];
    float b = red[4] + red[5] + red[6] + red[7];
    red[0] = a * (1.f / 1024.f);
    red[4] = b * (1.f / 1024.f);
  }
  __syncthreads();
  float mean = red[0];
  float var = red[4] - mean * mean;
  float rstd = rsqrtf(var + 1e-5f);
  float4 g = ((const float4*)gamma)[tid];
  float4 be = ((const float4*)beta)[tid];
  ushort4 o4;
  o4.x = f2bf((v.x - mean) * rstd * g.x + be.x);
  o4.y = f2bf((v.y - mean) * rstd * g.y + be.y);
  o4.z = f2bf((v.z - mean) * rstd * g.z + be.z);
  o4.w = f2bf((v.w - mean) * rstd * g.w + be.w);
  ((ushort4*)(ybf + (size_t)row * 1024))[tid] = o4;
}

// ---------------- launch ----------------
extern "C" void kernel_launch(void* const* d_in, const int* in_sizes, int n_in,
                              void* d_out, int out_size, void* d_ws, size_t ws_size,
                              hipStream_t stream) {
  const float* x = (const float*)d_in[0];
  const float* lb = (const float*)d_in[1];
  const float* Win = (const float*)d_in[2];
  const float* bin = (const float*)d_in[3];
  const float* Wout = (const float*)d_in[4];
  const float* bout = (const float*)d_in[5];
  const float* gamma = (const float*)d_in[6];
  const float* beta = (const float*)d_in[7];
  float* out = (float*)d_out;

  char* ws = (char*)d_ws;
  size_t off = 0;
  auto alloc = [&](size_t bytes) {
    void* p = ws + off;
    off += (bytes + 255) & ~(size_t)255;
    return p;
  };
  unsigned short* x_bf = (unsigned short*)alloc(8192ull * 1024 * 2);
  unsigned short* winT = (unsigned short*)alloc(3072ull * 1024 * 2);
  unsigned short* woutT = (unsigned short*)alloc(1024ull * 1024 * 2);
  float* inp_s = (float*)alloc(8192ull * 1024 * 4);
  float* og_s = (float*)alloc(8192ull * 1024 * 4);
  float* lam = (float*)alloc(8192ull * 1024 * 4);
  float* outp = (float*)alloc(8192ull * 1024 * 4);
  unsigned short* y_bf = (unsigned short*)alloc(8192ull * 1024 * 2);
  float* sumA = (float*)alloc(64ull * 4 * 512 * 2 * 4);
  float* sumBf = (float*)alloc(64ull * 4 * 512 * 4 * 4);
  float* sumBr = (float*)alloc(64ull * 4 * 512 * 4 * 4);
  float* initF = (float*)alloc(64ull * 4 * 512 * 4 * 4);
  float* initR = (float*)alloc(64ull * 4 * 512 * 4 * 4);

  cast_x_kernel<<<8192, 256, 0, stream>>>(x, x_bf);
  dim3 tb(32, 32);
  tcast_kernel<<<dim3(96, 32), tb, 0, stream>>>(Win, winT, 3072);
  tcast_kernel<<<dim3(32, 32), tb, 0, stream>>>(Wout, woutT, 1024);
  gemm_kernel<1><<<dim3(64, 24), 256, 0, stream>>>(x_bf, winT, bin, lb, inp_s, og_s, lam);
  scan_passA<<<512, 256, 0, stream>>>(lam, inp_s, sumA, sumBf, sumBr);
  scan_passB<<<64, 256, 0, stream>>>(sumA, sumBf, sumBr, initF, initR);
  scan_passC1<<<512, 256, 0, stream>>>(lam, inp_s, og_s, initF, outp);
  scan_passC2<<<512, 256, 0, stream>>>(lam, inp_s, og_s, initR, outp);
  ln_kernel<<<8192, 256, 0, stream>>>(outp, gamma, beta, y_bf);
  gemm_kernel<0><<<dim3(64, 8), 256, 0, stream>>>(y_bf, woutT, bout, nullptr, out, nullptr, nullptr);
}

// Round 2
// 288.243 us; speedup vs baseline: 1.1004x; 1.1004x over previous
//
#include <hip/hip_runtime.h>

typedef __bf16 bf16x8 __attribute__((ext_vector_type(8)));
typedef float floatx4 __attribute__((ext_vector_type(4)));

#define NCH 64   // number of time chunks
#define CLEN 32  // chunk length (NCH*CLEN = 2048)

__device__ __forceinline__ unsigned short f2bf(float f) {
  unsigned int u = __builtin_bit_cast(unsigned int, f);
  u += 0x7fff + ((u >> 16) & 1);
  return (unsigned short)(u >> 16);
}

// async 16B global->LDS copy; LDS dest = wave-uniform base + lane*16
__device__ __forceinline__ void async_copy16(const void* g, void* l) {
  __builtin_amdgcn_global_load_lds(
      (const __attribute__((address_space(1))) unsigned int*)g,
      (__attribute__((address_space(3))) unsigned int*)l, 16, 0, 0);
}

// ---------------- casts ----------------
__global__ void cast_x_kernel(const float* __restrict__ in, unsigned short* __restrict__ out) {
  int i = blockIdx.x * blockDim.x + threadIdx.x;  // exact: 8192 blk * 256 thr * 4 elems
  float4 v = ((const float4*)in)[i];
  ushort4 o;
  o.x = f2bf(v.x); o.y = f2bf(v.y); o.z = f2bf(v.z); o.w = f2bf(v.w);
  ((ushort4*)out)[i] = o;
}

// W (1024 x ncols) fp32 -> WT (ncols x 1024) bf16
__global__ void tcast_kernel(const float* __restrict__ W, unsigned short* __restrict__ WT, int ncols) {
  __shared__ float tile[32][33];
  int n0 = blockIdx.x * 32, k0 = blockIdx.y * 32;
  int tx = threadIdx.x, ty = threadIdx.y;
  tile[ty][tx] = W[(size_t)(k0 + ty) * ncols + n0 + tx];
  __syncthreads();
  WT[(size_t)(n0 + ty) * 1024 + k0 + tx] = f2bf(tile[tx][ty]);
}

// ---------------- GEMM (bf16 MFMA, K=1024 fixed) ----------------
// global_load_lds staging (width=16) with XOR chunk swizzle:
// chunk (row, q) lives at LDS As[row*32 + (q ^ ((row>>1)&3))*8]
// EPI==1: gemm1 epilogue -> silu/sigmoid/lam.  EPI==0: gemm2 -> out + bias.
template <int EPI>
__global__ __launch_bounds__(256) void gemm_kernel(
    const unsigned short* __restrict__ A, const unsigned short* __restrict__ BT,
    const float* __restrict__ bias, const float* __restrict__ lb,
    float* __restrict__ out0, float* __restrict__ out1, float* __restrict__ out2) {
  __shared__ alignas(16) unsigned short As[128 * 32];
  __shared__ alignas(16) unsigned short Bs[128 * 32];
  const int m0 = blockIdx.x * 128, n0 = blockIdx.y * 128;
  const int tid = threadIdx.x;
  const int lane = tid & 63, wave = tid >> 6;
  const int wm = (wave >> 1) * 64, wn = (wave & 1) * 64;
  const int mrow = lane & 15, q = lane >> 4;
  const int qsw = q ^ ((mrow >> 1) & 3);  // read-side swizzled chunk position
  floatx4 acc[4][4] = {};
  // staging: wave w covers rows [w*32, w*32+32); 2 instrs of 16 rows per matrix
  const int r0 = wave * 32;
  const int srow = r0 + (lane >> 2);
  const int qs = (lane & 3) ^ ((srow >> 1) & 3);  // global chunk this lane fetches
  const unsigned short* gA0 = A + (size_t)(m0 + srow) * 1024 + qs * 8;
  const unsigned short* gA1 = gA0 + (size_t)16 * 1024;
  const unsigned short* gB0 = BT + (size_t)(n0 + srow) * 1024 + qs * 8;
  const unsigned short* gB1 = gB0 + (size_t)16 * 1024;
  unsigned short* lA0 = &As[r0 * 32];
  unsigned short* lA1 = &As[(r0 + 16) * 32];
  unsigned short* lB0 = &Bs[r0 * 32];
  unsigned short* lB1 = &Bs[(r0 + 16) * 32];
  for (int kt = 0; kt < 1024; kt += 32) {
    __syncthreads();  // previous tile fully consumed
    async_copy16(gA0, lA0);
    async_copy16(gA1, lA1);
    async_copy16(gB0, lB0);
    async_copy16(gB1, lB1);
    gA0 += 32; gA1 += 32; gB0 += 32; gB1 += 32;
    __syncthreads();  // drains vmcnt -> staging complete
    bf16x8 af[4], bf[4];
#pragma unroll
    for (int i = 0; i < 4; i++) af[i] = *(const bf16x8*)&As[(wm + i * 16 + mrow) * 32 + qsw * 8];
#pragma unroll
    for (int j = 0; j < 4; j++) bf[j] = *(const bf16x8*)&Bs[(wn + j * 16 + mrow) * 32 + qsw * 8];
#pragma unroll
    for (int i = 0; i < 4; i++)
#pragma unroll
      for (int j = 0; j < 4; j++)
        acc[i][j] = __builtin_amdgcn_mfma_f32_16x16x32_bf16(af[i], bf[j], acc[i][j], 0, 0, 0);
  }
#pragma unroll
  for (int i = 0; i < 4; i++) {
    const int rbase = m0 + wm + i * 16 + q * 4;
#pragma unroll
    for (int j = 0; j < 4; j++) {
      const int c = n0 + wn + j * 16 + mrow;
      const float bi = bias[c];
#pragma unroll
      for (int g = 0; g < 4; g++) {
        float v = acc[i][j][g] + bi;
        size_t ro = (size_t)(rbase + g) * 1024;
        if (EPI == 0) {
          out0[ro + c] = v;
        } else {
          int segc = c >> 10, cl = c & 1023;
          float s = 1.f / (1.f + __expf(-v));
          if (segc == 0) out0[ro + cl] = v * s;                       // silu(inp)
          else if (segc == 1) out1[ro + cl] = s;                     // sigmoid(og)
          else { float L = lb[cl]; out2[ro + cl] = L + (1.f - L) * s; } // lam
        }
      }
    }
  }
}

// ---------------- chunked bidirectional scan ----------------
// channel layout per (b,h): ch = dd*2+e;  a=lam[dd], u=(1-lam[dd])*inp[e]
// idx = (c*4 + b)*512 + h
__global__ void scan_passA(const float* __restrict__ lam, const float* __restrict__ inp,
                           float* __restrict__ sumA, float* __restrict__ sumBf,
                           float* __restrict__ sumBr) {
  int idx = blockIdx.x * 256 + threadIdx.x;
  int h = idx & 511, cb = idx >> 9, b = cb & 3, c = cb >> 2;
  long base = ((long)c * CLEN * 4 + b) * 1024 + 2 * h;
  float p0 = 1.f, p1 = 1.f;
  float s00 = 0.f, s01 = 0.f, s10 = 0.f, s11 = 0.f;
  float r00 = 0.f, r01 = 0.f, r10 = 0.f, r11 = 0.f;
  for (int t = 0; t < CLEN; t++) {
    float2 l = *(const float2*)(lam + base);
    float2 ip = *(const float2*)(inp + base);
    base += 4096;
    float omx = 1.f - l.x, omy = 1.f - l.y;
    float u00 = omx * ip.x, u01 = omx * ip.y, u10 = omy * ip.x, u11 = omy * ip.y;
    r00 += p0 * u00; r01 += p0 * u01; r10 += p1 * u10; r11 += p1 * u11;
    s00 = l.x * s00 + u00; s01 = l.x * s01 + u01;
    s10 = l.y * s10 + u10; s11 = l.y * s11 + u11;
    p0 *= l.x; p1 *= l.y;
  }
  ((float2*)sumA)[idx] = make_float2(p0, p1);
  ((float4*)sumBf)[idx] = make_float4(s00, s01, s10, s11);
  ((float4*)sumBr)[idx] = make_float4(r00, r01, r10, r11);
}

__global__ void scan_passB(const float* __restrict__ sumA, const float* __restrict__ sumBf,
                           const float* __restrict__ sumBr, float* __restrict__ initF,
                           float* __restrict__ initR) {
  int tid = blockIdx.x * 256 + threadIdx.x;  // 16384
  int dir = tid >> 13;
  int rem = tid & 8191;   // (b*512+h)*4 + ch
  int ch = rem & 3;
  int bh = rem >> 2;
  int dd = ch >> 1;
  if (dir == 0) {
    float H = 0.f;
    for (int c = 0; c < NCH; c++) {
      int si = c * 2048 + bh;
      initF[(size_t)si * 4 + ch] = H;
      H = sumA[(size_t)si * 2 + dd] * H + sumBf[(size_t)si * 4 + ch];
    }
  } else {
    float G = 0.f;
    for (int c = NCH - 1; c >= 0; c--) {
      int si = c * 2048 + bh;
      initR[(size_t)si * 4 + ch] = G;
      G = sumA[(size_t)si * 2 + dd] * G + sumBr[(size_t)si * 4 + ch];
    }
  }
}

__global__ void scan_passC1(const float* __restrict__ lam, const float* __restrict__ inp,
                            const float* __restrict__ og, const float* __restrict__ initF,
                            float* __restrict__ outp) {
  int idx = blockIdx.x * 256 + threadIdx.x;
  int h = idx & 511, cb = idx >> 9, b = cb & 3, c = cb >> 2;
  float4 H = ((const float4*)initF)[idx];
  float h00 = H.x, h01 = H.y, h10 = H.z, h11 = H.w;
  long base = ((long)c * CLEN * 4 + b) * 1024 + 2 * h;
  for (int t = 0; t < CLEN; t++) {
    float2 l = *(const float2*)(lam + base);
    float2 ip = *(const float2*)(inp + base);
    float2 o = *(const float2*)(og + base);
    float omx = 1.f - l.x, omy = 1.f - l.y;
    h00 = l.x * h00 + omx * ip.x; h01 = l.x * h01 + omx * ip.y;
    h10 = l.y * h10 + omy * ip.x; h11 = l.y * h11 + omy * ip.y;
    float2 rr;
    rr.x = h00 * o.x + h10 * o.y;
    rr.y = h01 * o.x + h11 * o.y;
    *(float2*)(outp + base) = rr;
    base += 4096;
  }
}

__global__ void scan_passC2(const float* __restrict__ lam, const float* __restrict__ inp,
                            const float* __restrict__ og, const float* __restrict__ initR,
                            float* __restrict__ outp) {
  int idx = blockIdx.x * 256 + threadIdx.x;
  int h = idx & 511, cb = idx >> 9, b = cb & 3, c = cb >> 2;
  float4 G = ((const float4*)initR)[idx];
  float g00 = G.x, g01 = G.y, g10 = G.z, g11 = G.w;
  long base = ((long)(c * CLEN + CLEN - 1) * 4 + b) * 1024 + 2 * h;
  for (int t = 0; t < CLEN; t++) {
    float2 l = *(const float2*)(lam + base);
    float2 ip = *(const float2*)(inp + base);
    float2 o = *(const float2*)(og + base);
    float2 pv = *(const float2*)(outp + base);
    float omx = 1.f - l.x, omy = 1.f - l.y;
    g00 = omx * ip.x + l.x * g00; g01 = omx * ip.y + l.x * g01;
    g10 = omy * ip.x + l.y * g10; g11 = omy * ip.y + l.y * g11;
    float2 rr;
    rr.x = pv.x + g00 * o.x + g10 * o.y;
    rr.y = pv.y + g01 * o.x + g11 * o.y;
    *(float2*)(outp + base) = rr;
    base -= 4096;
  }
}

// ---------------- layernorm -> bf16 ----------------
__global__ void ln_kernel(const float* __restrict__ xin, const float* __restrict__ gamma,
                          const float* __restrict__ beta, unsigned short* __restrict__ ybf) {
  int row = blockIdx.x;
  int tid = threadIdx.x;
  float4 v = ((const float4*)(xin + (size_t)row * 1024))[tid];
  float s = v.x + v.y + v.z + v.w;
  float s2 = v.x * v.x + v.y * v.y + v.z * v.z + v.w * v.w;
#pragma unroll
  for (int o = 32; o > 0; o >>= 1) { s += __shfl_down(s, o); s2 += __shfl_down(s2, o); }
  __shared__ float red[8];
  int lane = tid & 63, w = tid >> 6;
  if (lane == 0) { red[w] = s; red[w + 4] = s2; }
  __syncthreads();
  if (tid == 0) {
    float a = red[0] + red[1] + red[2] + red[3];
    float b = red[4] + red[5] + red[6] + red[7];
    red[0] = a * (1.f / 1024.f);
    red[4] = b * (1.f / 1024.f);
  }
  __syncthreads();
  float mean = red[0];
  float var = red[4] - mean * mean;
  float rstd = rsqrtf(var + 1e-5f);
  float4 g = ((const float4*)gamma)[tid];
  float4 be = ((const float4*)beta)[tid];
  ushort4 o4;
  o4.x = f2bf((v.x - mean) * rstd * g.x + be.x);
  o4.y = f2bf((v.y - mean) * rstd * g.y + be.y);
  o4.z = f2bf((v.z - mean) * rstd * g.z + be.z);
  o4.w = f2bf((v.w - mean) * rstd * g.w + be.w);
  ((ushort4*)(ybf + (size_t)row * 1024))[tid] = o4;
}

// ---------------- launch ----------------
extern "C" void kernel_launch(void* const* d_in, const int* in_sizes, int n_in,
                              void* d_out, int out_size, void* d_ws, size_t ws_size,
                              hipStream_t stream) {
  const float* x = (const float*)d_in[0];
  const float* lb = (const float*)d_in[1];
  const float* Win = (const float*)d_in[2];
  const float* bin = (const float*)d_in[3];
  const float* Wout = (const float*)d_in[4];
  const float* bout = (const float*)d_in[5];
  const float* gamma = (const float*)d_in[6];
  const float* beta = (const float*)d_in[7];
  float* out = (float*)d_out;

  char* ws = (char*)d_ws;
  size_t off = 0;
  auto alloc = [&](size_t bytes) {
    void* p = ws + off;
    off += (bytes + 255) & ~(size_t)255;
    return p;
  };
  unsigned short* x_bf = (unsigned short*)alloc(8192ull * 1024 * 2);
  unsigned short* winT = (unsigned short*)alloc(3072ull * 1024 * 2);
  unsigned short* woutT = (unsigned short*)alloc(1024ull * 1024 * 2);
  float* inp_s = (float*)alloc(8192ull * 1024 * 4);
  float* og_s = (float*)alloc(8192ull * 1024 * 4);
  float* lam = (float*)alloc(8192ull * 1024 * 4);
  float* outp = (float*)alloc(8192ull * 1024 * 4);
  unsigned short* y_bf = (unsigned short*)alloc(8192ull * 1024 * 2);
  float* sumA = (float*)alloc(64ull * 4 * 512 * 2 * 4);
  float* sumBf = (float*)alloc(64ull * 4 * 512 * 4 * 4);
  float* sumBr = (float*)alloc(64ull * 4 * 512 * 4 * 4);
  float* initF = (float*)alloc(64ull * 4 * 512 * 4 * 4);
  float* initR = (float*)alloc(64ull * 4 * 512 * 4 * 4);

  cast_x_kernel<<<8192, 256, 0, stream>>>(x, x_bf);
  dim3 tb(32, 32);
  tcast_kernel<<<dim3(96, 32), tb, 0, stream>>>(Win, winT, 3072);
  tcast_kernel<<<dim3(32, 32), tb, 0, stream>>>(Wout, woutT, 1024);
  gemm_kernel<1><<<dim3(64, 24), 256, 0, stream>>>(x_bf, winT, bin, lb, inp_s, og_s, lam);
  scan_passA<<<512, 256, 0, stream>>>(lam, inp_s, sumA, sumBf, sumBr);
  scan_passB<<<64, 256, 0, stream>>>(sumA, sumBf, sumBr, initF, initR);
  scan_passC1<<<512, 256, 0, stream>>>(lam, inp_s, og_s, initF, outp);
  scan_passC2<<<512, 256, 0, stream>>>(lam, inp_s, og_s, initR, outp);
  ln_kernel<<<8192, 256, 0, stream>>>(outp, gamma, beta, y_bf);
  gemm_kernel<0><<<dim3(64, 8), 256, 0, stream>>>(y_bf, woutT, bout, nullptr, out, nullptr, nullptr);
}

// Round 4
// 261.977 us; speedup vs baseline: 1.2107x; 1.1003x over previous
//
#include <hip/hip_runtime.h>

typedef __bf16 bf16x8 __attribute__((ext_vector_type(8)));
typedef float floatx4 __attribute__((ext_vector_type(4)));

#define NCH 128  // number of time chunks
#define CLEN 16  // chunk length (NCH*CLEN = 2048)

__device__ __forceinline__ unsigned short f2bf(float f) {
  unsigned int u = __builtin_bit_cast(unsigned int, f);
  u += 0x7fff + ((u >> 16) & 1);
  return (unsigned short)(u >> 16);
}
__device__ __forceinline__ float bf2f(unsigned short u) {
  unsigned int v = (unsigned int)u << 16;
  return __builtin_bit_cast(float, v);
}

// async 16B global->LDS copy; LDS dest = wave-uniform base + lane*16
__device__ __forceinline__ void async_copy16(const void* g, void* l) {
  __builtin_amdgcn_global_load_lds(
      (const __attribute__((address_space(1))) unsigned int*)g,
      (__attribute__((address_space(3))) unsigned int*)l, 16, 0, 0);
}

// ---------------- casts ----------------
__global__ void cast_x_kernel(const float* __restrict__ in, unsigned short* __restrict__ out) {
  int i = blockIdx.x * blockDim.x + threadIdx.x;  // exact: 8192 blk * 256 thr * 4 elems
  float4 v = ((const float4*)in)[i];
  ushort4 o;
  o.x = f2bf(v.x); o.y = f2bf(v.y); o.z = f2bf(v.z); o.w = f2bf(v.w);
  ((ushort4*)out)[i] = o;
}

// W (1024 x ncols) fp32 -> WT (ncols x 1024) bf16
__global__ void tcast_kernel(const float* __restrict__ W, unsigned short* __restrict__ WT, int ncols) {
  __shared__ float tile[32][33];
  int n0 = blockIdx.x * 32, k0 = blockIdx.y * 32;
  int tx = threadIdx.x, ty = threadIdx.y;
  tile[ty][tx] = W[(size_t)(k0 + ty) * ncols + n0 + tx];
  __syncthreads();
  WT[(size_t)(n0 + ty) * 1024 + k0 + tx] = f2bf(tile[tx][ty]);
}

// ---------------- GEMM (bf16 MFMA, K=1024 fixed) ----------------
// global_load_lds staging (width=16) with XOR chunk swizzle:
// chunk (row, q) lives at LDS As[row*32 + (q ^ ((row>>1)&3))*8]
// EPI==1: gemm1 epilogue -> bf16 silu(inp) / sigmoid(og) / om=1-lam.
// EPI==0: gemm2 -> fp32 out + bias.
template <int EPI>
__global__ __launch_bounds__(256) void gemm_kernel(
    const unsigned short* __restrict__ A, const unsigned short* __restrict__ BT,
    const float* __restrict__ bias, const float* __restrict__ lb,
    float* __restrict__ outf,
    unsigned short* __restrict__ o_inp, unsigned short* __restrict__ o_og,
    unsigned short* __restrict__ o_om) {
  __shared__ alignas(16) unsigned short As[128 * 32];
  __shared__ alignas(16) unsigned short Bs[128 * 32];
  const int m0 = blockIdx.x * 128, n0 = blockIdx.y * 128;
  const int tid = threadIdx.x;
  const int lane = tid & 63, wave = tid >> 6;
  const int wm = (wave >> 1) * 64, wn = (wave & 1) * 64;
  const int mrow = lane & 15, q = lane >> 4;
  const int qsw = q ^ ((mrow >> 1) & 3);  // read-side swizzled chunk position
  floatx4 acc[4][4] = {};
  // staging: wave w covers rows [w*32, w*32+32); 2 instrs of 16 rows per matrix
  const int r0 = wave * 32;
  const int srow = r0 + (lane >> 2);
  const int qs = (lane & 3) ^ ((srow >> 1) & 3);  // global chunk this lane fetches
  const unsigned short* gA0 = A + (size_t)(m0 + srow) * 1024 + qs * 8;
  const unsigned short* gA1 = gA0 + (size_t)16 * 1024;
  const unsigned short* gB0 = BT + (size_t)(n0 + srow) * 1024 + qs * 8;
  const unsigned short* gB1 = gB0 + (size_t)16 * 1024;
  unsigned short* lA0 = &As[r0 * 32];
  unsigned short* lA1 = &As[(r0 + 16) * 32];
  unsigned short* lB0 = &Bs[r0 * 32];
  unsigned short* lB1 = &Bs[(r0 + 16) * 32];
  for (int kt = 0; kt < 1024; kt += 32) {
    __syncthreads();  // previous tile fully consumed
    async_copy16(gA0, lA0);
    async_copy16(gA1, lA1);
    async_copy16(gB0, lB0);
    async_copy16(gB1, lB1);
    gA0 += 32; gA1 += 32; gB0 += 32; gB1 += 32;
    __syncthreads();  // drains vmcnt -> staging complete
    bf16x8 af[4], bf[4];
#pragma unroll
    for (int i = 0; i < 4; i++) af[i] = *(const bf16x8*)&As[(wm + i * 16 + mrow) * 32 + qsw * 8];
#pragma unroll
    for (int j = 0; j < 4; j++) bf[j] = *(const bf16x8*)&Bs[(wn + j * 16 + mrow) * 32 + qsw * 8];
#pragma unroll
    for (int i = 0; i < 4; i++)
#pragma unroll
      for (int j = 0; j < 4; j++)
        acc[i][j] = __builtin_amdgcn_mfma_f32_16x16x32_bf16(af[i], bf[j], acc[i][j], 0, 0, 0);
  }
#pragma unroll
  for (int i = 0; i < 4; i++) {
    const int rbase = m0 + wm + i * 16 + q * 4;
#pragma unroll
    for (int j = 0; j < 4; j++) {
      const int c = n0 + wn + j * 16 + mrow;
      const float bi = bias[c];
#pragma unroll
      for (int g = 0; g < 4; g++) {
        float v = acc[i][j][g] + bi;
        size_t ro = (size_t)(rbase + g) * 1024;
        if (EPI == 0) {
          outf[ro + c] = v;
        } else {
          int segc = c >> 10, cl = c & 1023;
          if (segc == 0) {
            float s = 1.f / (1.f + __expf(-v));
            o_inp[ro + cl] = f2bf(v * s);                 // silu(inp)
          } else if (segc == 1) {
            float s = 1.f / (1.f + __expf(-v));
            o_og[ro + cl] = f2bf(s);                      // sigmoid(og)
          } else {
            float sm = 1.f / (1.f + __expf(v));           // sigma(-v) = 1-sigma(v)
            float L = lb[cl];
            o_om[ro + cl] = f2bf((1.f - L) * sm);         // om = 1-lam, stable near 0
          }
        }
      }
    }
  }
}

// ---------------- chunked bidirectional scan ----------------
// channel layout per (b,h): ch = dd*2+e;  a=lam[dd]=1-om[dd], u=om[dd]*inp[e]
// idx = (c*4 + b)*512 + h
__global__ void scan_passA(const unsigned short* __restrict__ om, const unsigned short* __restrict__ ip,
                           float* __restrict__ sumA, float* __restrict__ sumBf,
                           float* __restrict__ sumBr) {
  int idx = blockIdx.x * 256 + threadIdx.x;
  int h = idx & 511, cb = idx >> 9, b = cb & 3, c = cb >> 2;
  long base = ((long)c * CLEN * 4 + b) * 1024 + 2 * h;
  float p0 = 1.f, p1 = 1.f;
  float s00 = 0.f, s01 = 0.f, s10 = 0.f, s11 = 0.f;
  float r00 = 0.f, r01 = 0.f, r10 = 0.f, r11 = 0.f;
#pragma unroll
  for (int t = 0; t < CLEN; t++) {
    ushort2 l2 = *(const ushort2*)(om + base);
    ushort2 i2 = *(const ushort2*)(ip + base);
    base += 4096;
    float omx = bf2f(l2.x), omy = bf2f(l2.y);
    float ipx = bf2f(i2.x), ipy = bf2f(i2.y);
    float lx = 1.f - omx, ly = 1.f - omy;
    float u00 = omx * ipx, u01 = omx * ipy, u10 = omy * ipx, u11 = omy * ipy;
    r00 += p0 * u00; r01 += p0 * u01; r10 += p1 * u10; r11 += p1 * u11;
    s00 = lx * s00 + u00; s01 = lx * s01 + u01;
    s10 = ly * s10 + u10; s11 = ly * s11 + u11;
    p0 *= lx; p1 *= ly;
  }
  ((float2*)sumA)[idx] = make_float2(p0, p1);
  ((float4*)sumBf)[idx] = make_float4(s00, s01, s10, s11);
  ((float4*)sumBr)[idx] = make_float4(r00, r01, r10, r11);
}

__global__ void scan_passB(const float* __restrict__ sumA, const float* __restrict__ sumBf,
                           const float* __restrict__ sumBr, float* __restrict__ initF,
                           float* __restrict__ initR) {
  int tid = blockIdx.x * 256 + threadIdx.x;  // 16384
  int dir = tid >> 13;
  int rem = tid & 8191;   // (b*512+h)*4 + ch
  int ch = rem & 3;
  int bh = rem >> 2;
  int dd = ch >> 1;
  if (dir == 0) {
    float H = 0.f;
    for (int c = 0; c < NCH; c++) {
      int si = c * 2048 + bh;
      initF[(size_t)si * 4 + ch] = H;
      H = sumA[(size_t)si * 2 + dd] * H + sumBf[(size_t)si * 4 + ch];
    }
  } else {
    float G = 0.f;
    for (int c = NCH - 1; c >= 0; c--) {
      int si = c * 2048 + bh;
      initR[(size_t)si * 4 + ch] = G;
      G = sumA[(size_t)si * 2 + dd] * G + sumBr[(size_t)si * 4 + ch];
    }
  }
}

// ---- fused replay (fwd+rev) + layernorm -> bf16 y ----
// one block per (c,b): 512 threads, thread = h. out stash in VGPRs,
// LN via 8-row LDS transpose groups.
__global__ __launch_bounds__(512) void scanC_ln_kernel(
    const unsigned short* __restrict__ om, const unsigned short* __restrict__ ip,
    const unsigned short* __restrict__ og,
    const float* __restrict__ initF, const float* __restrict__ initR,
    const float* __restrict__ gamma, const float* __restrict__ beta,
    unsigned short* __restrict__ ybf) {
  __shared__ float tile[8][1024];
  __shared__ float ldsG[1024];
  __shared__ float ldsB[1024];
  const int h = threadIdx.x;  // 0..511
  const int cb = blockIdx.x;  // c*4 + b
  const int b = cb & 3, c = cb >> 2;
  const int idx = cb * 512 + h;
  // preload gamma/beta
  *(float2*)&ldsG[2 * h] = *(const float2*)(gamma + 2 * h);
  *(float2*)&ldsB[2 * h] = *(const float2*)(beta + 2 * h);
  float4 F = ((const float4*)initF)[idx];
  float4 R = ((const float4*)initR)[idx];
  float outx[CLEN], outy[CLEN];
  const long base = ((long)c * CLEN * 4 + b) * 1024 + 2 * h;
  float h00 = F.x, h01 = F.y, h10 = F.z, h11 = F.w;
  long p = base;
#pragma unroll
  for (int t = 0; t < CLEN; t++) {
    ushort2 l2 = *(const ushort2*)(om + p);
    ushort2 i2 = *(const ushort2*)(ip + p);
    ushort2 o2 = *(const ushort2*)(og + p);
    p += 4096;
    float omx = bf2f(l2.x), omy = bf2f(l2.y);
    float ipx = bf2f(i2.x), ipy = bf2f(i2.y);
    float ox = bf2f(o2.x), oy = bf2f(o2.y);
    float lx = 1.f - omx, ly = 1.f - omy;
    h00 = lx * h00 + omx * ipx; h01 = lx * h01 + omx * ipy;
    h10 = ly * h10 + omy * ipx; h11 = ly * h11 + omy * ipy;
    outx[t] = h00 * ox + h10 * oy;
    outy[t] = h01 * ox + h11 * oy;
  }
  float g00 = R.x, g01 = R.y, g10 = R.z, g11 = R.w;
  p = base + (CLEN - 1) * 4096;
#pragma unroll
  for (int t = CLEN - 1; t >= 0; t--) {
    ushort2 l2 = *(const ushort2*)(om + p);
    ushort2 i2 = *(const ushort2*)(ip + p);
    ushort2 o2 = *(const ushort2*)(og + p);
    p -= 4096;
    float omx = bf2f(l2.x), omy = bf2f(l2.y);
    float ipx = bf2f(i2.x), ipy = bf2f(i2.y);
    float ox = bf2f(o2.x), oy = bf2f(o2.y);
    float lx = 1.f - omx, ly = 1.f - omy;
    g00 = omx * ipx + lx * g00; g01 = omx * ipy + lx * g01;
    g10 = omy * ipx + ly * g10; g11 = omy * ipy + ly * g11;
    outx[t] += g00 * ox + g10 * oy;
    outy[t] += g01 * ox + g11 * oy;
  }
  // layernorm in groups of 8 t-rows via LDS transpose
  const int lane = h & 63, wv = h >> 6;
#pragma unroll
  for (int g = 0; g < CLEN / 8; g++) {
    __syncthreads();  // prior group reads done (and gamma/beta preload on g=0)
#pragma unroll
    for (int r = 0; r < 8; r++) {
      float2 v2 = make_float2(outx[g * 8 + r], outy[g * 8 + r]);
      *(float2*)&tile[r][2 * h] = v2;
    }
    __syncthreads();
    // wave wv reduces + normalizes row wv of this group
    {
      const int t = g * 8 + wv;
      float4 v[4];
#pragma unroll
      for (int k = 0; k < 4; k++) v[k] = *(const float4*)&tile[wv][lane * 16 + k * 4];
      float s = 0.f, s2 = 0.f;
#pragma unroll
      for (int k = 0; k < 4; k++) {
        s += v[k].x + v[k].y + v[k].z + v[k].w;
        s2 += v[k].x * v[k].x + v[k].y * v[k].y + v[k].z * v[k].z + v[k].w * v[k].w;
      }
#pragma unroll
      for (int off = 1; off < 64; off <<= 1) {
        s += __shfl_xor(s, off);
        s2 += __shfl_xor(s2, off);
      }
      float mean = s * (1.f / 1024.f);
      float var = s2 * (1.f / 1024.f) - mean * mean;
      float rstd = rsqrtf(var + 1e-5f);
      unsigned short o16[16];
#pragma unroll
      for (int k = 0; k < 4; k++) {
        float* vv = (float*)&v[k];
#pragma unroll
        for (int e = 0; e < 4; e++) {
          int ch = lane * 16 + k * 4 + e;
          o16[k * 4 + e] = f2bf((vv[e] - mean) * rstd * ldsG[ch] + ldsB[ch]);
        }
      }
      size_t rowo = ((size_t)(c * CLEN + t) * 4 + b) * 1024 + lane * 16;
      *(uint4*)(ybf + rowo) = *(uint4*)&o16[0];
      *(uint4*)(ybf + rowo + 8) = *(uint4*)&o16[8];
    }
  }
}

// ---------------- launch ----------------
extern "C" void kernel_launch(void* const* d_in, const int* in_sizes, int n_in,
                              void* d_out, int out_size, void* d_ws, size_t ws_size,
                              hipStream_t stream) {
  const float* x = (const float*)d_in[0];
  const float* lb = (const float*)d_in[1];
  const float* Win = (const float*)d_in[2];
  const float* bin = (const float*)d_in[3];
  const float* Wout = (const float*)d_in[4];
  const float* bout = (const float*)d_in[5];
  const float* gamma = (const float*)d_in[6];
  const float* beta = (const float*)d_in[7];
  float* out = (float*)d_out;

  char* ws = (char*)d_ws;
  size_t off = 0;
  auto alloc = [&](size_t bytes) {
    void* p = ws + off;
    off += (bytes + 255) & ~(size_t)255;
    return p;
  };
  unsigned short* x_bf = (unsigned short*)alloc(8192ull * 1024 * 2);
  unsigned short* winT = (unsigned short*)alloc(3072ull * 1024 * 2);
  unsigned short* woutT = (unsigned short*)alloc(1024ull * 1024 * 2);
  unsigned short* inp_b = (unsigned short*)alloc(8192ull * 1024 * 2);
  unsigned short* og_b = (unsigned short*)alloc(8192ull * 1024 * 2);
  unsigned short* om_b = (unsigned short*)alloc(8192ull * 1024 * 2);
  unsigned short* y_bf = (unsigned short*)alloc(8192ull * 1024 * 2);
  float* sumA = (float*)alloc((size_t)NCH * 4 * 512 * 2 * 4);
  float* sumBf = (float*)alloc((size_t)NCH * 4 * 512 * 4 * 4);
  float* sumBr = (float*)alloc((size_t)NCH * 4 * 512 * 4 * 4);
  float* initF = (float*)alloc((size_t)NCH * 4 * 512 * 4 * 4);
  float* initR = (float*)alloc((size_t)NCH * 4 * 512 * 4 * 4);

  cast_x_kernel<<<8192, 256, 0, stream>>>(x, x_bf);
  dim3 tb(32, 32);
  tcast_kernel<<<dim3(96, 32), tb, 0, stream>>>(Win, winT, 3072);
  tcast_kernel<<<dim3(32, 32), tb, 0, stream>>>(Wout, woutT, 1024);
  gemm_kernel<1><<<dim3(64, 24), 256, 0, stream>>>(x_bf, winT, bin, lb, nullptr, inp_b, og_b, om_b);
  scan_passA<<<(NCH * 4 * 512) / 256, 256, 0, stream>>>(om_b, inp_b, sumA, sumBf, sumBr);
  scan_passB<<<64, 256, 0, stream>>>(sumA, sumBf, sumBr, initF, initR);
  scanC_ln_kernel<<<NCH * 4, 512, 0, stream>>>(om_b, inp_b, og_b, initF, initR, gamma, beta, y_bf);
  gemm_kernel<0><<<dim3(64, 8), 256, 0, stream>>>(y_bf, woutT, bout, nullptr, out, nullptr, nullptr, nullptr);
}

// Round 5
// 247.382 us; speedup vs baseline: 1.2822x; 1.0590x over previous
//
#include <hip/hip_runtime.h>

typedef __bf16 bf16x8 __attribute__((ext_vector_type(8)));
typedef float floatx4 __attribute__((ext_vector_type(4)));

#define NCH 128  // number of time chunks
#define CLEN 16  // chunk length (NCH*CLEN = 2048)

__device__ __forceinline__ unsigned short f2bf(float f) {
  unsigned int u = __builtin_bit_cast(unsigned int, f);
  u += 0x7fff + ((u >> 16) & 1);
  return (unsigned short)(u >> 16);
}
__device__ __forceinline__ float bf2f(unsigned short u) {
  unsigned int v = (unsigned int)u << 16;
  return __builtin_bit_cast(float, v);
}

// async 16B global->LDS copy; LDS dest = wave-uniform base + lane*16
__device__ __forceinline__ void async_copy16(const void* g, void* l) {
  __builtin_amdgcn_global_load_lds(
      (const __attribute__((address_space(1))) unsigned int*)g,
      (__attribute__((address_space(3))) unsigned int*)l, 16, 0, 0);
}

// ---------------- casts ----------------
__global__ void cast_x_kernel(const float* __restrict__ in, unsigned short* __restrict__ out) {
  int i = blockIdx.x * blockDim.x + threadIdx.x;  // exact: 8192 blk * 256 thr * 4 elems
  float4 v = ((const float4*)in)[i];
  ushort4 o;
  o.x = f2bf(v.x); o.y = f2bf(v.y); o.z = f2bf(v.z); o.w = f2bf(v.w);
  ((ushort4*)out)[i] = o;
}

// W (1024 x ncols) fp32 -> WT (ncols x 1024) bf16
__global__ void tcast_kernel(const float* __restrict__ W, unsigned short* __restrict__ WT, int ncols) {
  __shared__ float tile[32][33];
  int n0 = blockIdx.x * 32, k0 = blockIdx.y * 32;
  int tx = threadIdx.x, ty = threadIdx.y;
  tile[ty][tx] = W[(size_t)(k0 + ty) * ncols + n0 + tx];
  __syncthreads();
  WT[(size_t)(n0 + ty) * 1024 + k0 + tx] = f2bf(tile[tx][ty]);
}

// ---------------- GEMM (bf16 MFMA, K=1024 fixed) ----------------
// global_load_lds staging (width=16) with XOR chunk swizzle:
// chunk (row, q) lives at LDS As[row*32 + (q ^ ((row>>1)&3))*8]
// Epilogue: activation -> LDS tile (padded) -> coalesced 32B/lane stores.
// EPI==1: gemm1 -> bf16 silu(inp) / sigmoid(og) / om=1-lam (segment is
// block-uniform since n0 % 128 == 0 and segments are 1024 wide).
// EPI==0: gemm2 -> fp32 out + bias.
template <int EPI>
__global__ __launch_bounds__(256) void gemm_kernel(
    const unsigned short* __restrict__ A, const unsigned short* __restrict__ BT,
    const float* __restrict__ bias, const float* __restrict__ lb,
    float* __restrict__ outf,
    unsigned short* __restrict__ o_inp, unsigned short* __restrict__ o_og,
    unsigned short* __restrict__ o_om) {
  __shared__ alignas(16) char smem_raw[17408];  // staging 16KB | epi tile (<=16.9KB)
  unsigned short* As = (unsigned short*)smem_raw;
  unsigned short* Bs = As + 128 * 32;
  const int m0 = blockIdx.x * 128, n0 = blockIdx.y * 128;
  const int tid = threadIdx.x;
  const int lane = tid & 63, wave = tid >> 6;
  const int wm = (wave >> 1) * 64, wn = (wave & 1) * 64;
  const int mrow = lane & 15, q = lane >> 4;
  const int qsw = q ^ ((mrow >> 1) & 3);  // read-side swizzled chunk position
  floatx4 acc[4][4] = {};
  // staging: wave w covers rows [w*32, w*32+32); 2 instrs of 16 rows per matrix
  const int r0 = wave * 32;
  const int srow = r0 + (lane >> 2);
  const int qs = (lane & 3) ^ ((srow >> 1) & 3);  // global chunk this lane fetches
  const unsigned short* gA0 = A + (size_t)(m0 + srow) * 1024 + qs * 8;
  const unsigned short* gA1 = gA0 + (size_t)16 * 1024;
  const unsigned short* gB0 = BT + (size_t)(n0 + srow) * 1024 + qs * 8;
  const unsigned short* gB1 = gB0 + (size_t)16 * 1024;
  unsigned short* lA0 = &As[r0 * 32];
  unsigned short* lA1 = &As[(r0 + 16) * 32];
  unsigned short* lB0 = &Bs[r0 * 32];
  unsigned short* lB1 = &Bs[(r0 + 16) * 32];
  for (int kt = 0; kt < 1024; kt += 32) {
    __syncthreads();  // previous tile fully consumed
    async_copy16(gA0, lA0);
    async_copy16(gA1, lA1);
    async_copy16(gB0, lB0);
    async_copy16(gB1, lB1);
    gA0 += 32; gA1 += 32; gB0 += 32; gB1 += 32;
    __syncthreads();  // drains vmcnt -> staging complete
    bf16x8 af[4], bf[4];
#pragma unroll
    for (int i = 0; i < 4; i++) af[i] = *(const bf16x8*)&As[(wm + i * 16 + mrow) * 32 + qsw * 8];
#pragma unroll
    for (int j = 0; j < 4; j++) bf[j] = *(const bf16x8*)&Bs[(wn + j * 16 + mrow) * 32 + qsw * 8];
#pragma unroll
    for (int i = 0; i < 4; i++)
#pragma unroll
      for (int j = 0; j < 4; j++)
        acc[i][j] = __builtin_amdgcn_mfma_f32_16x16x32_bf16(af[i], bf[j], acc[i][j], 0, 0, 0);
  }
  // ---- epilogue ----
  const int er = tid >> 3;            // 0..31: local row for coalesced store
  const int ec = (tid & 7) * 16;      // 0..112: col chunk base
  const int rgbase = m0 + (er & 15) + (er >> 4) * 64;  // + i*16 later
  const int lr = (wm ? 16 : 0) + q * 4;                // local row base for C writes
  float bi[4];
  int cidx[4];
#pragma unroll
  for (int j = 0; j < 4; j++) {
    cidx[j] = n0 + wn + j * 16 + mrow;
    bi[j] = bias[cidx[j]];
  }
  if (EPI == 1) {
    unsigned short* Cs = (unsigned short*)smem_raw;  // 32 x 136 bf16
    const int seg = n0 >> 10;
    unsigned short* dst = (seg == 0) ? o_inp : (seg == 1) ? o_og : o_om;
    float Lv[4];
    if (seg == 2) {
#pragma unroll
      for (int j = 0; j < 4; j++) Lv[j] = lb[cidx[j] & 1023];
    }
#pragma unroll
    for (int i = 0; i < 4; i++) {
      __syncthreads();
#pragma unroll
      for (int j = 0; j < 4; j++) {
        const int lc = wn + j * 16 + mrow;
#pragma unroll
        for (int g = 0; g < 4; g++) {
          float v = acc[i][j][g] + bi[j];
          unsigned short ob;
          if (seg == 0) { float s = 1.f / (1.f + __expf(-v)); ob = f2bf(v * s); }
          else if (seg == 1) { float s = 1.f / (1.f + __expf(-v)); ob = f2bf(s); }
          else { float sm = 1.f / (1.f + __expf(v)); ob = f2bf((1.f - Lv[j]) * sm); }
          Cs[(lr + g) * 136 + lc] = ob;
        }
      }
      __syncthreads();
      uint4 v0 = *(uint4*)&Cs[er * 136 + ec];
      uint4 v1 = *(uint4*)&Cs[er * 136 + ec + 8];
      size_t ro = (size_t)(rgbase + i * 16) * 1024 + (n0 & 1023) + ec;
      *(uint4*)&dst[ro] = v0;
      *(uint4*)&dst[ro + 8] = v1;
    }
  } else {
    float* Cf = (float*)smem_raw;  // 32 x 132 fp32
#pragma unroll
    for (int i = 0; i < 4; i++) {
      __syncthreads();
#pragma unroll
      for (int j = 0; j < 4; j++) {
        const int lc = wn + j * 16 + mrow;
#pragma unroll
        for (int g = 0; g < 4; g++) Cf[(lr + g) * 132 + lc] = acc[i][j][g] + bi[j];
      }
      __syncthreads();
      size_t ro = (size_t)(rgbase + i * 16) * 1024 + n0 + ec;
#pragma unroll
      for (int k = 0; k < 4; k++) {
        float4 v = *(float4*)&Cf[er * 132 + ec + k * 4];
        *(float4*)&outf[ro + k * 4] = v;
      }
    }
  }
}

// ---------------- chunked bidirectional scan ----------------
// channel layout per (b,h): ch = dd*2+e;  a=lam[dd]=1-om[dd], u=om[dd]*inp[e]
// idx = (c*4 + b)*512 + h
__global__ void scan_passA(const unsigned short* __restrict__ om, const unsigned short* __restrict__ ip,
                           float* __restrict__ sumA, float* __restrict__ sumBf,
                           float* __restrict__ sumBr) {
  int idx = blockIdx.x * 256 + threadIdx.x;
  int h = idx & 511, cb = idx >> 9, b = cb & 3, c = cb >> 2;
  long base = ((long)c * CLEN * 4 + b) * 1024 + 2 * h;
  float p0 = 1.f, p1 = 1.f;
  float s00 = 0.f, s01 = 0.f, s10 = 0.f, s11 = 0.f;
  float r00 = 0.f, r01 = 0.f, r10 = 0.f, r11 = 0.f;
#pragma unroll
  for (int t = 0; t < CLEN; t++) {
    ushort2 l2 = *(const ushort2*)(om + base);
    ushort2 i2 = *(const ushort2*)(ip + base);
    base += 4096;
    float omx = bf2f(l2.x), omy = bf2f(l2.y);
    float ipx = bf2f(i2.x), ipy = bf2f(i2.y);
    float lx = 1.f - omx, ly = 1.f - omy;
    float u00 = omx * ipx, u01 = omx * ipy, u10 = omy * ipx, u11 = omy * ipy;
    r00 += p0 * u00; r01 += p0 * u01; r10 += p1 * u10; r11 += p1 * u11;
    s00 = lx * s00 + u00; s01 = lx * s01 + u01;
    s10 = ly * s10 + u10; s11 = ly * s11 + u11;
    p0 *= lx; p1 *= ly;
  }
  ((float2*)sumA)[idx] = make_float2(p0, p1);
  ((float4*)sumBf)[idx] = make_float4(s00, s01, s10, s11);
  ((float4*)sumBr)[idx] = make_float4(r00, r01, r10, r11);
}

__global__ void scan_passB(const float* __restrict__ sumA, const float* __restrict__ sumBf,
                           const float* __restrict__ sumBr, float* __restrict__ initF,
                           float* __restrict__ initR) {
  int tid = blockIdx.x * 256 + threadIdx.x;  // 16384
  int dir = tid >> 13;
  int rem = tid & 8191;   // (b*512+h)*4 + ch
  int ch = rem & 3;
  int bh = rem >> 2;
  int dd = ch >> 1;
  if (dir == 0) {
    float H = 0.f;
    for (int c = 0; c < NCH; c++) {
      int si = c * 2048 + bh;
      initF[(size_t)si * 4 + ch] = H;
      H = sumA[(size_t)si * 2 + dd] * H + sumBf[(size_t)si * 4 + ch];
    }
  } else {
    float G = 0.f;
    for (int c = NCH - 1; c >= 0; c--) {
      int si = c * 2048 + bh;
      initR[(size_t)si * 4 + ch] = G;
      G = sumA[(size_t)si * 2 + dd] * G + sumBr[(size_t)si * 4 + ch];
    }
  }
}

// ---- fused replay (fwd+rev) + layernorm -> bf16 y ----
// one block per (c,b): 512 threads, thread = h. out stash in VGPRs,
// LN via 8-row LDS transpose groups.
__global__ __launch_bounds__(512) void scanC_ln_kernel(
    const unsigned short* __restrict__ om, const unsigned short* __restrict__ ip,
    const unsigned short* __restrict__ og,
    const float* __restrict__ initF, const float* __restrict__ initR,
    const float* __restrict__ gamma, const float* __restrict__ beta,
    unsigned short* __restrict__ ybf) {
  __shared__ float tile[8][1024];
  __shared__ float ldsG[1024];
  __shared__ float ldsB[1024];
  const int h = threadIdx.x;  // 0..511
  const int cb = blockIdx.x;  // c*4 + b
  const int b = cb & 3, c = cb >> 2;
  const int idx = cb * 512 + h;
  // preload gamma/beta
  *(float2*)&ldsG[2 * h] = *(const float2*)(gamma + 2 * h);
  *(float2*)&ldsB[2 * h] = *(const float2*)(beta + 2 * h);
  float4 F = ((const float4*)initF)[idx];
  float4 R = ((const float4*)initR)[idx];
  float outx[CLEN], outy[CLEN];
  const long base = ((long)c * CLEN * 4 + b) * 1024 + 2 * h;
  float h00 = F.x, h01 = F.y, h10 = F.z, h11 = F.w;
  long p = base;
#pragma unroll
  for (int t = 0; t < CLEN; t++) {
    ushort2 l2 = *(const ushort2*)(om + p);
    ushort2 i2 = *(const ushort2*)(ip + p);
    ushort2 o2 = *(const ushort2*)(og + p);
    p += 4096;
    float omx = bf2f(l2.x), omy = bf2f(l2.y);
    float ipx = bf2f(i2.x), ipy = bf2f(i2.y);
    float ox = bf2f(o2.x), oy = bf2f(o2.y);
    float lx = 1.f - omx, ly = 1.f - omy;
    h00 = lx * h00 + omx * ipx; h01 = lx * h01 + omx * ipy;
    h10 = ly * h10 + omy * ipx; h11 = ly * h11 + omy * ipy;
    outx[t] = h00 * ox + h10 * oy;
    outy[t] = h01 * ox + h11 * oy;
  }
  float g00 = R.x, g01 = R.y, g10 = R.z, g11 = R.w;
  p = base + (CLEN - 1) * 4096;
#pragma unroll
  for (int t = CLEN - 1; t >= 0; t--) {
    ushort2 l2 = *(const ushort2*)(om + p);
    ushort2 i2 = *(const ushort2*)(ip + p);
    ushort2 o2 = *(const ushort2*)(og + p);
    p -= 4096;
    float omx = bf2f(l2.x), omy = bf2f(l2.y);
    float ipx = bf2f(i2.x), ipy = bf2f(i2.y);
    float ox = bf2f(o2.x), oy = bf2f(o2.y);
    float lx = 1.f - omx, ly = 1.f - omy;
    g00 = omx * ipx + lx * g00; g01 = omx * ipy + lx * g01;
    g10 = omy * ipx + ly * g10; g11 = omy * ipy + ly * g11;
    outx[t] += g00 * ox + g10 * oy;
    outy[t] += g01 * ox + g11 * oy;
  }
  // layernorm in groups of 8 t-rows via LDS transpose
  const int lane = h & 63, wv = h >> 6;
#pragma unroll
  for (int g = 0; g < CLEN / 8; g++) {
    __syncthreads();  // prior group reads done (and gamma/beta preload on g=0)
#pragma unroll
    for (int r = 0; r < 8; r++) {
      float2 v2 = make_float2(outx[g * 8 + r], outy[g * 8 + r]);
      *(float2*)&tile[r][2 * h] = v2;
    }
    __syncthreads();
    // wave wv reduces + normalizes row wv of this group
    {
      const int t = g * 8 + wv;
      float4 v[4];
#pragma unroll
      for (int k = 0; k < 4; k++) v[k] = *(const float4*)&tile[wv][lane * 16 + k * 4];
      float s = 0.f, s2 = 0.f;
#pragma unroll
      for (int k = 0; k < 4; k++) {
        s += v[k].x + v[k].y + v[k].z + v[k].w;
        s2 += v[k].x * v[k].x + v[k].y * v[k].y + v[k].z * v[k].z + v[k].w * v[k].w;
      }
#pragma unroll
      for (int off = 1; off < 64; off <<= 1) {
        s += __shfl_xor(s, off);
        s2 += __shfl_xor(s2, off);
      }
      float mean = s * (1.f / 1024.f);
      float var = s2 * (1.f / 1024.f) - mean * mean;
      float rstd = rsqrtf(var + 1e-5f);
      unsigned short o16[16];
#pragma unroll
      for (int k = 0; k < 4; k++) {
        float* vv = (float*)&v[k];
#pragma unroll
        for (int e = 0; e < 4; e++) {
          int ch = lane * 16 + k * 4 + e;
          o16[k * 4 + e] = f2bf((vv[e] - mean) * rstd * ldsG[ch] + ldsB[ch]);
        }
      }
      size_t rowo = ((size_t)(c * CLEN + t) * 4 + b) * 1024 + lane * 16;
      *(uint4*)(ybf + rowo) = *(uint4*)&o16[0];
      *(uint4*)(ybf + rowo + 8) = *(uint4*)&o16[8];
    }
  }
}

// ---------------- launch ----------------
extern "C" void kernel_launch(void* const* d_in, const int* in_sizes, int n_in,
                              void* d_out, int out_size, void* d_ws, size_t ws_size,
                              hipStream_t stream) {
  const float* x = (const float*)d_in[0];
  const float* lb = (const float*)d_in[1];
  const float* Win = (const float*)d_in[2];
  const float* bin = (const float*)d_in[3];
  const float* Wout = (const float*)d_in[4];
  const float* bout = (const float*)d_in[5];
  const float* gamma = (const float*)d_in[6];
  const float* beta = (const float*)d_in[7];
  float* out = (float*)d_out;

  char* ws = (char*)d_ws;
  size_t off = 0;
  auto alloc = [&](size_t bytes) {
    void* p = ws + off;
    off += (bytes + 255) & ~(size_t)255;
    return p;
  };
  unsigned short* x_bf = (unsigned short*)alloc(8192ull * 1024 * 2);
  unsigned short* winT = (unsigned short*)alloc(3072ull * 1024 * 2);
  unsigned short* woutT = (unsigned short*)alloc(1024ull * 1024 * 2);
  unsigned short* inp_b = (unsigned short*)alloc(8192ull * 1024 * 2);
  unsigned short* og_b = (unsigned short*)alloc(8192ull * 1024 * 2);
  unsigned short* om_b = (unsigned short*)alloc(8192ull * 1024 * 2);
  unsigned short* y_bf = (unsigned short*)alloc(8192ull * 1024 * 2);
  float* sumA = (float*)alloc((size_t)NCH * 4 * 512 * 2 * 4);
  float* sumBf = (float*)alloc((size_t)NCH * 4 * 512 * 4 * 4);
  float* sumBr = (float*)alloc((size_t)NCH * 4 * 512 * 4 * 4);
  float* initF = (float*)alloc((size_t)NCH * 4 * 512 * 4 * 4);
  float* initR = (float*)alloc((size_t)NCH * 4 * 512 * 4 * 4);

  cast_x_kernel<<<8192, 256, 0, stream>>>(x, x_bf);
  dim3 tb(32, 32);
  tcast_kernel<<<dim3(96, 32), tb, 0, stream>>>(Win, winT, 3072);
  tcast_kernel<<<dim3(32, 32), tb, 0, stream>>>(Wout, woutT, 1024);
  gemm_kernel<1><<<dim3(64, 24), 256, 0, stream>>>(x_bf, winT, bin, lb, nullptr, inp_b, og_b, om_b);
  scan_passA<<<(NCH * 4 * 512) / 256, 256, 0, stream>>>(om_b, inp_b, sumA, sumBf, sumBr);
  scan_passB<<<64, 256, 0, stream>>>(sumA, sumBf, sumBr, initF, initR);
  scanC_ln_kernel<<<NCH * 4, 512, 0, stream>>>(om_b, inp_b, og_b, initF, initR, gamma, beta, y_bf);
  gemm_kernel<0><<<dim3(64, 8), 256, 0, stream>>>(y_bf, woutT, bout, nullptr, out, nullptr, nullptr, nullptr);
}

// Round 6
// 243.125 us; speedup vs baseline: 1.3046x; 1.0175x over previous
//
#include <hip/hip_runtime.h>

typedef __bf16 bf16x8 __attribute__((ext_vector_type(8)));
typedef float floatx4 __attribute__((ext_vector_type(4)));

#define NCH 128  // number of time chunks
#define CLEN 16  // chunk length (NCH*CLEN = 2048)

__device__ __forceinline__ unsigned short f2bf(float f) {
  unsigned int u = __builtin_bit_cast(unsigned int, f);
  u += 0x7fff + ((u >> 16) & 1);
  return (unsigned short)(u >> 16);
}
__device__ __forceinline__ float bf2f(unsigned short u) {
  unsigned int v = (unsigned int)u << 16;
  return __builtin_bit_cast(float, v);
}
__device__ __forceinline__ float bf2f_lo(unsigned int u) {
  return __builtin_bit_cast(float, u << 16);
}
__device__ __forceinline__ float bf2f_hi(unsigned int u) {
  return __builtin_bit_cast(float, u & 0xffff0000u);
}

// async 16B global->LDS copy; LDS dest = wave-uniform base + lane*16
__device__ __forceinline__ void async_copy16(const void* g, void* l) {
  __builtin_amdgcn_global_load_lds(
      (const __attribute__((address_space(1))) unsigned int*)g,
      (__attribute__((address_space(3))) unsigned int*)l, 16, 0, 0);
}

// ---------------- casts ----------------
__global__ void cast_x_kernel(const float* __restrict__ in, unsigned short* __restrict__ out) {
  int i = blockIdx.x * blockDim.x + threadIdx.x;  // exact: 8192 blk * 256 thr * 4 elems
  float4 v = ((const float4*)in)[i];
  ushort4 o;
  o.x = f2bf(v.x); o.y = f2bf(v.y); o.z = f2bf(v.z); o.w = f2bf(v.w);
  ((ushort4*)out)[i] = o;
}

// both weights: W (1024 x ncols) fp32 -> WT (ncols x 1024) bf16, one launch
__global__ void tcast2_kernel(const float* __restrict__ Win, unsigned short* __restrict__ winT,
                              const float* __restrict__ Wout, unsigned short* __restrict__ woutT) {
  __shared__ float tile[32][33];
  int bx = blockIdx.x;
  const float* W;
  unsigned short* WT;
  int ncols, n0;
  if (bx < 96) { W = Win; WT = winT; ncols = 3072; n0 = bx * 32; }
  else { W = Wout; WT = woutT; ncols = 1024; n0 = (bx - 96) * 32; }
  int k0 = blockIdx.y * 32;
  int tx = threadIdx.x, ty = threadIdx.y;
  tile[ty][tx] = W[(size_t)(k0 + ty) * ncols + n0 + tx];
  __syncthreads();
  WT[(size_t)(n0 + ty) * 1024 + k0 + tx] = f2bf(tile[tx][ty]);
}

// ---------------- GEMM (bf16 MFMA, K=1024 fixed) ----------------
// global_load_lds staging (width=16) with XOR chunk swizzle:
// chunk (row, q) lives at LDS As[row*32 + (q ^ ((row>>1)&3))*8]
// Epilogue: activation -> LDS tile (padded) -> coalesced 32B/lane stores.
// EPI==1: gemm1 -> bf16 silu(inp) / sigmoid(og) / om=1-lam (segment is
// block-uniform since n0 % 128 == 0 and segments are 1024 wide).
// EPI==0: gemm2 -> fp32 out + bias.
template <int EPI>
__global__ __launch_bounds__(256) void gemm_kernel(
    const unsigned short* __restrict__ A, const unsigned short* __restrict__ BT,
    const float* __restrict__ bias, const float* __restrict__ lb,
    float* __restrict__ outf,
    unsigned short* __restrict__ o_inp, unsigned short* __restrict__ o_og,
    unsigned short* __restrict__ o_om) {
  __shared__ alignas(16) char smem_raw[17408];  // staging 16KB | epi tile (<=16.9KB)
  unsigned short* As = (unsigned short*)smem_raw;
  unsigned short* Bs = As + 128 * 32;
  const int m0 = blockIdx.x * 128, n0 = blockIdx.y * 128;
  const int tid = threadIdx.x;
  const int lane = tid & 63, wave = tid >> 6;
  const int wm = (wave >> 1) * 64, wn = (wave & 1) * 64;
  const int mrow = lane & 15, q = lane >> 4;
  const int qsw = q ^ ((mrow >> 1) & 3);  // read-side swizzled chunk position
  floatx4 acc[4][4] = {};
  // staging: wave w covers rows [w*32, w*32+32); 2 instrs of 16 rows per matrix
  const int r0 = wave * 32;
  const int srow = r0 + (lane >> 2);
  const int qs = (lane & 3) ^ ((srow >> 1) & 3);  // global chunk this lane fetches
  const unsigned short* gA0 = A + (size_t)(m0 + srow) * 1024 + qs * 8;
  const unsigned short* gA1 = gA0 + (size_t)16 * 1024;
  const unsigned short* gB0 = BT + (size_t)(n0 + srow) * 1024 + qs * 8;
  const unsigned short* gB1 = gB0 + (size_t)16 * 1024;
  unsigned short* lA0 = &As[r0 * 32];
  unsigned short* lA1 = &As[(r0 + 16) * 32];
  unsigned short* lB0 = &Bs[r0 * 32];
  unsigned short* lB1 = &Bs[(r0 + 16) * 32];
  for (int kt = 0; kt < 1024; kt += 32) {
    __syncthreads();  // previous tile fully consumed
    async_copy16(gA0, lA0);
    async_copy16(gA1, lA1);
    async_copy16(gB0, lB0);
    async_copy16(gB1, lB1);
    gA0 += 32; gA1 += 32; gB0 += 32; gB1 += 32;
    __syncthreads();  // drains vmcnt -> staging complete
    bf16x8 af[4], bf[4];
#pragma unroll
    for (int i = 0; i < 4; i++) af[i] = *(const bf16x8*)&As[(wm + i * 16 + mrow) * 32 + qsw * 8];
#pragma unroll
    for (int j = 0; j < 4; j++) bf[j] = *(const bf16x8*)&Bs[(wn + j * 16 + mrow) * 32 + qsw * 8];
#pragma unroll
    for (int i = 0; i < 4; i++)
#pragma unroll
      for (int j = 0; j < 4; j++)
        acc[i][j] = __builtin_amdgcn_mfma_f32_16x16x32_bf16(af[i], bf[j], acc[i][j], 0, 0, 0);
  }
  // ---- epilogue ----
  const int er = tid >> 3;            // 0..31: local row for coalesced store
  const int ec = (tid & 7) * 16;      // 0..112: col chunk base
  const int rgbase = m0 + (er & 15) + (er >> 4) * 64;  // + i*16 later
  const int lr = (wm ? 16 : 0) + q * 4;                // local row base for C writes
  float bi[4];
  int cidx[4];
#pragma unroll
  for (int j = 0; j < 4; j++) {
    cidx[j] = n0 + wn + j * 16 + mrow;
    bi[j] = bias[cidx[j]];
  }
  if (EPI == 1) {
    unsigned short* Cs = (unsigned short*)smem_raw;  // 32 x 136 bf16
    const int seg = n0 >> 10;
    unsigned short* dst = (seg == 0) ? o_inp : (seg == 1) ? o_og : o_om;
    float Lv[4];
    if (seg == 2) {
#pragma unroll
      for (int j = 0; j < 4; j++) Lv[j] = lb[cidx[j] & 1023];
    }
#pragma unroll
    for (int i = 0; i < 4; i++) {
      __syncthreads();
#pragma unroll
      for (int j = 0; j < 4; j++) {
        const int lc = wn + j * 16 + mrow;
#pragma unroll
        for (int g = 0; g < 4; g++) {
          float v = acc[i][j][g] + bi[j];
          unsigned short ob;
          if (seg == 0) { float s = 1.f / (1.f + __expf(-v)); ob = f2bf(v * s); }
          else if (seg == 1) { float s = 1.f / (1.f + __expf(-v)); ob = f2bf(s); }
          else { float sm = 1.f / (1.f + __expf(v)); ob = f2bf((1.f - Lv[j]) * sm); }
          Cs[(lr + g) * 136 + lc] = ob;
        }
      }
      __syncthreads();
      uint4 v0 = *(uint4*)&Cs[er * 136 + ec];
      uint4 v1 = *(uint4*)&Cs[er * 136 + ec + 8];
      size_t ro = (size_t)(rgbase + i * 16) * 1024 + (n0 & 1023) + ec;
      *(uint4*)&dst[ro] = v0;
      *(uint4*)&dst[ro + 8] = v1;
    }
  } else {
    float* Cf = (float*)smem_raw;  // 32 x 132 fp32
#pragma unroll
    for (int i = 0; i < 4; i++) {
      __syncthreads();
#pragma unroll
      for (int j = 0; j < 4; j++) {
        const int lc = wn + j * 16 + mrow;
#pragma unroll
        for (int g = 0; g < 4; g++) Cf[(lr + g) * 132 + lc] = acc[i][j][g] + bi[j];
      }
      __syncthreads();
      size_t ro = (size_t)(rgbase + i * 16) * 1024 + n0 + ec;
#pragma unroll
      for (int k = 0; k < 4; k++) {
        float4 v = *(float4*)&Cf[er * 132 + ec + k * 4];
        *(float4*)&outf[ro + k * 4] = v;
      }
    }
  }
}

// ---------------- chunked bidirectional scan ----------------
// channel layout per (b,h): ch = dd*2+e;  a=lam[dd]=1-om[dd], u=om[dd]*inp[e]
// idx = (c*4 + b)*512 + h
__global__ void scan_passA(const unsigned short* __restrict__ om, const unsigned short* __restrict__ ip,
                           float* __restrict__ sumA, float* __restrict__ sumBf,
                           float* __restrict__ sumBr) {
  int idx = blockIdx.x * 256 + threadIdx.x;
  int h = idx & 511, cb = idx >> 9, b = cb & 3, c = cb >> 2;
  long base = ((long)c * CLEN * 4 + b) * 1024 + 2 * h;
  float p0 = 1.f, p1 = 1.f;
  float s00 = 0.f, s01 = 0.f, s10 = 0.f, s11 = 0.f;
  float r00 = 0.f, r01 = 0.f, r10 = 0.f, r11 = 0.f;
#pragma unroll
  for (int t = 0; t < CLEN; t++) {
    ushort2 l2 = *(const ushort2*)(om + base);
    ushort2 i2 = *(const ushort2*)(ip + base);
    base += 4096;
    float omx = bf2f(l2.x), omy = bf2f(l2.y);
    float ipx = bf2f(i2.x), ipy = bf2f(i2.y);
    float lx = 1.f - omx, ly = 1.f - omy;
    float u00 = omx * ipx, u01 = omx * ipy, u10 = omy * ipx, u11 = omy * ipy;
    r00 += p0 * u00; r01 += p0 * u01; r10 += p1 * u10; r11 += p1 * u11;
    s00 = lx * s00 + u00; s01 = lx * s01 + u01;
    s10 = ly * s10 + u10; s11 = ly * s11 + u11;
    p0 *= lx; p1 *= ly;
  }
  ((float2*)sumA)[idx] = make_float2(p0, p1);
  ((float4*)sumBf)[idx] = make_float4(s00, s01, s10, s11);
  ((float4*)sumBr)[idx] = make_float4(r00, r01, r10, r11);
}

__global__ void scan_passB(const float* __restrict__ sumA, const float* __restrict__ sumBf,
                           const float* __restrict__ sumBr, float* __restrict__ initF,
                           float* __restrict__ initR) {
  int tid = blockIdx.x * 256 + threadIdx.x;  // 16384
  int dir = tid >> 13;
  int rem = tid & 8191;   // (b*512+h)*4 + ch
  int ch = rem & 3;
  int bh = rem >> 2;
  int dd = ch >> 1;
  if (dir == 0) {
    float H = 0.f;
    for (int c = 0; c < NCH; c++) {
      int si = c * 2048 + bh;
      initF[(size_t)si * 4 + ch] = H;
      H = sumA[(size_t)si * 2 + dd] * H + sumBf[(size_t)si * 4 + ch];
    }
  } else {
    float G = 0.f;
    for (int c = NCH - 1; c >= 0; c--) {
      int si = c * 2048 + bh;
      initR[(size_t)si * 4 + ch] = G;
      G = sumA[(size_t)si * 2 + dd] * G + sumBr[(size_t)si * 4 + ch];
    }
  }
}

// ---- fused replay (fwd+rev) + layernorm -> bf16 y ----
// one block per (c,b): 512 threads, thread = h. Inputs loaded ONCE in the
// fwd loop and stashed in VGPRs (16 x 3 packed uints); rev loop replays
// from registers. LN via 8-row LDS transpose groups.
__global__ __launch_bounds__(512) void scanC_ln_kernel(
    const unsigned short* __restrict__ om, const unsigned short* __restrict__ ip,
    const unsigned short* __restrict__ og,
    const float* __restrict__ initF, const float* __restrict__ initR,
    const float* __restrict__ gamma, const float* __restrict__ beta,
    unsigned short* __restrict__ ybf) {
  __shared__ float tile[8][1024];
  __shared__ float ldsG[1024];
  __shared__ float ldsB[1024];
  const int h = threadIdx.x;  // 0..511
  const int cb = blockIdx.x;  // c*4 + b
  const int b = cb & 3, c = cb >> 2;
  const int idx = cb * 512 + h;
  // preload gamma/beta
  *(float2*)&ldsG[2 * h] = *(const float2*)(gamma + 2 * h);
  *(float2*)&ldsB[2 * h] = *(const float2*)(beta + 2 * h);
  float4 F = ((const float4*)initF)[idx];
  float4 R = ((const float4*)initR)[idx];
  float outx[CLEN], outy[CLEN];
  unsigned int lS[CLEN], iS[CLEN], oS[CLEN];
  const long base = ((long)c * CLEN * 4 + b) * 1024 + 2 * h;
  float h00 = F.x, h01 = F.y, h10 = F.z, h11 = F.w;
  long p = base;
#pragma unroll
  for (int t = 0; t < CLEN; t++) {
    unsigned int l2 = *(const unsigned int*)(om + p);
    unsigned int i2 = *(const unsigned int*)(ip + p);
    unsigned int o2 = *(const unsigned int*)(og + p);
    p += 4096;
    lS[t] = l2; iS[t] = i2; oS[t] = o2;
    float omx = bf2f_lo(l2), omy = bf2f_hi(l2);
    float ipx = bf2f_lo(i2), ipy = bf2f_hi(i2);
    float ox = bf2f_lo(o2), oy = bf2f_hi(o2);
    float lx = 1.f - omx, ly = 1.f - omy;
    h00 = lx * h00 + omx * ipx; h01 = lx * h01 + omx * ipy;
    h10 = ly * h10 + omy * ipx; h11 = ly * h11 + omy * ipy;
    outx[t] = h00 * ox + h10 * oy;
    outy[t] = h01 * ox + h11 * oy;
  }
  float g00 = R.x, g01 = R.y, g10 = R.z, g11 = R.w;
#pragma unroll
  for (int t = CLEN - 1; t >= 0; t--) {
    unsigned int l2 = lS[t], i2 = iS[t], o2 = oS[t];
    float omx = bf2f_lo(l2), omy = bf2f_hi(l2);
    float ipx = bf2f_lo(i2), ipy = bf2f_hi(i2);
    float ox = bf2f_lo(o2), oy = bf2f_hi(o2);
    float lx = 1.f - omx, ly = 1.f - omy;
    g00 = omx * ipx + lx * g00; g01 = omx * ipy + lx * g01;
    g10 = omy * ipx + ly * g10; g11 = omy * ipy + ly * g11;
    outx[t] += g00 * ox + g10 * oy;
    outy[t] += g01 * ox + g11 * oy;
  }
  // layernorm in groups of 8 t-rows via LDS transpose
  const int lane = h & 63, wv = h >> 6;
#pragma unroll
  for (int g = 0; g < CLEN / 8; g++) {
    __syncthreads();  // prior group reads done (and gamma/beta preload on g=0)
#pragma unroll
    for (int r = 0; r < 8; r++) {
      float2 v2 = make_float2(outx[g * 8 + r], outy[g * 8 + r]);
      *(float2*)&tile[r][2 * h] = v2;
    }
    __syncthreads();
    // wave wv reduces + normalizes row wv of this group
    {
      const int t = g * 8 + wv;
      float4 v[4];
#pragma unroll
      for (int k = 0; k < 4; k++) v[k] = *(const float4*)&tile[wv][lane * 16 + k * 4];
      float s = 0.f, s2 = 0.f;
#pragma unroll
      for (int k = 0; k < 4; k++) {
        s += v[k].x + v[k].y + v[k].z + v[k].w;
        s2 += v[k].x * v[k].x + v[k].y * v[k].y + v[k].z * v[k].z + v[k].w * v[k].w;
      }
#pragma unroll
      for (int off = 1; off < 64; off <<= 1) {
        s += __shfl_xor(s, off);
        s2 += __shfl_xor(s2, off);
      }
      float mean = s * (1.f / 1024.f);
      float var = s2 * (1.f / 1024.f) - mean * mean;
      float rstd = rsqrtf(var + 1e-5f);
      unsigned short o16[16];
#pragma unroll
      for (int k = 0; k < 4; k++) {
        float* vv = (float*)&v[k];
#pragma unroll
        for (int e = 0; e < 4; e++) {
          int ch = lane * 16 + k * 4 + e;
          o16[k * 4 + e] = f2bf((vv[e] - mean) * rstd * ldsG[ch] + ldsB[ch]);
        }
      }
      size_t rowo = ((size_t)(c * CLEN + t) * 4 + b) * 1024 + lane * 16;
      *(uint4*)(ybf + rowo) = *(uint4*)&o16[0];
      *(uint4*)(ybf + rowo + 8) = *(uint4*)&o16[8];
    }
  }
}

// ---------------- launch ----------------
extern "C" void kernel_launch(void* const* d_in, const int* in_sizes, int n_in,
                              void* d_out, int out_size, void* d_ws, size_t ws_size,
                              hipStream_t stream) {
  const float* x = (const float*)d_in[0];
  const float* lb = (const float*)d_in[1];
  const float* Win = (const float*)d_in[2];
  const float* bin = (const float*)d_in[3];
  const float* Wout = (const float*)d_in[4];
  const float* bout = (const float*)d_in[5];
  const float* gamma = (const float*)d_in[6];
  const float* beta = (const float*)d_in[7];
  float* out = (float*)d_out;

  char* ws = (char*)d_ws;
  size_t off = 0;
  auto alloc = [&](size_t bytes) {
    void* p = ws + off;
    off += (bytes + 255) & ~(size_t)255;
    return p;
  };
  unsigned short* x_bf = (unsigned short*)alloc(8192ull * 1024 * 2);
  unsigned short* winT = (unsigned short*)alloc(3072ull * 1024 * 2);
  unsigned short* woutT = (unsigned short*)alloc(1024ull * 1024 * 2);
  unsigned short* inp_b = (unsigned short*)alloc(8192ull * 1024 * 2);
  unsigned short* og_b = (unsigned short*)alloc(8192ull * 1024 * 2);
  unsigned short* om_b = (unsigned short*)alloc(8192ull * 1024 * 2);
  unsigned short* y_bf = (unsigned short*)alloc(8192ull * 1024 * 2);
  float* sumA = (float*)alloc((size_t)NCH * 4 * 512 * 2 * 4);
  float* sumBf = (float*)alloc((size_t)NCH * 4 * 512 * 4 * 4);
  float* sumBr = (float*)alloc((size_t)NCH * 4 * 512 * 4 * 4);
  float* initF = (float*)alloc((size_t)NCH * 4 * 512 * 4 * 4);
  float* initR = (float*)alloc((size_t)NCH * 4 * 512 * 4 * 4);

  cast_x_kernel<<<8192, 256, 0, stream>>>(x, x_bf);
  tcast2_kernel<<<dim3(128, 32), dim3(32, 32), 0, stream>>>(Win, winT, Wout, woutT);
  gemm_kernel<1><<<dim3(64, 24), 256, 0, stream>>>(x_bf, winT, bin, lb, nullptr, inp_b, og_b, om_b);
  scan_passA<<<(NCH * 4 * 512) / 256, 256, 0, stream>>>(om_b, inp_b, sumA, sumBf, sumBr);
  scan_passB<<<64, 256, 0, stream>>>(sumA, sumBf, sumBr, initF, initR);
  scanC_ln_kernel<<<NCH * 4, 512, 0, stream>>>(om_b, inp_b, og_b, initF, initR, gamma, beta, y_bf);
  gemm_kernel<0><<<dim3(64, 8), 256, 0, stream>>>(y_bf, woutT, bout, nullptr, out, nullptr, nullptr, nullptr);
}